// Round 1
// baseline (449.759 us; speedup 1.0000x reference)
//
#include <hip/hip_runtime.h>
#include <math.h>

// Problem constants (from reference): B=64, T=2000, V=29, L=200
#define Bn 64
#define Tn 2000
#define Vn 29
#define Ln 200
#define Sn (2 * Ln + 1)   // 401 lattice states
#define BLANKC 28
#define NEGF  (-1e30f)
#define EPSF  (1e-7f)
#define CHUNK 250         // time steps of log-probs staged in LDS per chunk
#define LPSTRIDE 33       // pad stride to avoid LDS bank conflicts

__global__ __launch_bounds__(512, 1)
void ctc_loss_kernel(const float* __restrict__ logits,
                     const int*   __restrict__ labels,
                     const int*   __restrict__ input_length,
                     const int*   __restrict__ label_length,
                     const int*   __restrict__ mts_ptr,
                     float*       __restrict__ out)
{
    // alpha double buffer, indexed A[buf][s+2]; A[buf][0..1] are -inf pads
    __shared__ float A[2][Sn + 2];
    __shared__ float LP[CHUNK][LPSTRIDE];  // log(softmax+eps) for chunk, [tloc][v]
    __shared__ int   EXT[Sn];

    const int b   = blockIdx.x;
    const int tid = threadIdx.x;
    const float* lg = logits + (size_t)b * Tn * Vn;

    // Build extended label sequence: blank, l1, blank, l2, ..., blank
    for (int s = tid; s < Sn; s += blockDim.x) {
        EXT[s] = (s & 1) ? labels[b * Ln + ((s - 1) >> 1)] : BLANKC;
    }
    if (tid < 2) { A[0][tid] = NEGF; A[1][tid] = NEGF; }
    __syncthreads();

    const int s = tid;
    int  ext_s = 0;
    bool skip  = false;
    if (s < Sn) {
        ext_s = EXT[s];
        skip  = (s >= 2) && (ext_s != BLANKC) && (ext_s != EXT[s - 2]);
    }

    // ctc_len = floor(input_length * T / max_time_steps), computed in fp32 like ref
    const int mts = *mts_ptr;
    const int il  = input_length[b];
    const int ctc_len = (int)floorf((float)(il * Tn) / (float)mts);
    const int tend = min(ctc_len, Tn);   // steps t=0..tend-1 are active

    for (int base = 0; base < tend; base += CHUNK) {
        const int fill_n = min(CHUNK, tend - base);

        // ---- cooperative fill: log(softmax(logits[b,t,:]) + eps) -> LDS ----
        for (int i = tid; i < fill_n; i += (int)blockDim.x) {
            const float* row = lg + (size_t)(base + i) * Vn;
            float x[Vn];
            float m = -INFINITY;
            #pragma unroll
            for (int v = 0; v < Vn; ++v) { x[v] = row[v]; m = fmaxf(m, x[v]); }
            float z = 0.f;
            #pragma unroll
            for (int v = 0; v < Vn; ++v) { x[v] = __expf(x[v] - m); z += x[v]; }
            const float rz = 1.0f / z;
            #pragma unroll
            for (int v = 0; v < Vn; ++v) LP[i][v] = __logf(x[v] * rz + EPSF);
        }
        __syncthreads();

        int t0 = base;
        if (base == 0) {
            // alpha_0: only states 0 and 1 are reachable
            if (s < Sn) {
                float a0 = NEGF;
                if (s <= 1) a0 = LP[0][ext_s];
                A[0][s + 2] = a0;
            }
            t0 = 1;
            __syncthreads();
        }

        const int tstop = min(base + CHUNK, tend);
        for (int t = t0; t < tstop; ++t) {
            const int cur = t & 1, prev = cur ^ 1;
            if (s < Sn) {
                const float a  = A[prev][s + 2];
                const float a1 = A[prev][s + 1];
                const float a2 = skip ? A[prev][s] : NEGF;
                const float m  = fmaxf(fmaxf(a, a1), a2);
                const float sum = __expf(a - m) + __expf(a1 - m) + __expf(a2 - m);
                A[cur][s + 2] = m + __logf(sum) + LP[t - base][ext_s];
            }
            __syncthreads();
        }
    }

    if (tid == 0) {
        const int ll = label_length[b];
        const int fbuf = (tend - 1) & 1;
        const float a1 = A[fbuf][2 * ll + 2];
        const int   i2 = max(2 * ll - 1, 0);
        const float a2 = A[fbuf][i2 + 2];
        const float m  = fmaxf(a1, a2);
        out[b] = -(m + __logf(__expf(a1 - m) + __expf(a2 - m)));
    }
}

extern "C" void kernel_launch(void* const* d_in, const int* in_sizes, int n_in,
                              void* d_out, int out_size, void* d_ws, size_t ws_size,
                              hipStream_t stream) {
    const float* logits       = (const float*)d_in[0];
    const int*   labels       = (const int*)d_in[1];
    const int*   input_length = (const int*)d_in[2];
    const int*   label_length = (const int*)d_in[3];
    const int*   mts          = (const int*)d_in[4];
    float* out = (float*)d_out;

    ctc_loss_kernel<<<Bn, 512, 0, stream>>>(logits, labels, input_length,
                                            label_length, mts, out);
}

// Round 3
// 391.185 us; speedup vs baseline: 1.1497x; 1.1497x over previous
//
#include <hip/hip_runtime.h>
#include <math.h>

// Problem constants: B=64, T=2000, V=29, L=200
#define Bn 64
#define Tn 2000
#define Vn 29
#define Ln 200
#define Sn 401            // 2L+1 lattice states
#define BLANKC 28
#define EPSF  1e-7f
#define CHUNK 128         // time steps of linear probs staged per LDS buffer
#define PSTR  33          // row stride (floats), conflict-friendly
#define KPL   7           // lattice states per lane (64*7 = 448 >= 401)
#define SENT  (-(1 << 20))  // exponent sentinel for all-zero lanes

__global__ __launch_bounds__(128, 1)
void ctc_bfp_kernel(const float* __restrict__ logits,
                    const int*   __restrict__ labels,
                    const int*   __restrict__ input_length,
                    const int*   __restrict__ label_length,
                    const int*   __restrict__ mts_ptr,
                    float*       __restrict__ out)
{
    __shared__ float P[2][CHUNK][PSTR];   // linear probs (softmax+eps), double-buffered
    __shared__ float AF[64 * KPL];        // final mantissas
    __shared__ int   EL[64];              // final per-lane exponents

    const int b    = blockIdx.x;
    const int tid  = threadIdx.x;
    const int wid  = tid >> 6;            // wave 0: DP, wave 1: staging
    const int lane = tid & 63;
    const float* lg  = logits + (size_t)b * Tn * Vn;
    const int*   lab = labels + b * Ln;

    const int mts = *mts_ptr;
    const int ctc_len = (int)floorf((float)(input_length[b] * Tn) / (float)mts);
    const int tend = min(max(ctc_len, 1), Tn);
    const int nch  = (tend + CHUNK - 1) / CHUNK;

    // per-lane lattice metadata: symbol index and skip-transition multiplier
    int   poff[KPL];
    float skipm[KPL];
    #pragma unroll
    for (int k = 0; k < KPL; ++k) {
        const int s = lane * KPL + k;
        int e = BLANKC; float sk = 0.f;
        if (s < Sn && (s & 1)) {
            const int li = (s - 1) >> 1;
            e = lab[li];
            if (s >= 3 && e != lab[li - 1]) sk = 1.f;   // labels are never blank
        }
        poff[k] = e; skipm[k] = sk;
    }

    // prologue: stage chunk 0 with all 128 threads (linear probs)
    {
        const int fill = min(CHUNK, tend);
        for (int i = tid; i < fill; i += 128) {
            const float* row = lg + (size_t)i * Vn;
            float x[Vn]; float m = -INFINITY;
            #pragma unroll
            for (int v = 0; v < Vn; ++v) { x[v] = row[v]; m = fmaxf(m, x[v]); }
            float z = 0.f;
            #pragma unroll
            for (int v = 0; v < Vn; ++v) { x[v] = __expf(x[v] - m); z += x[v]; }
            const float rz = 1.0f / z;
            #pragma unroll
            for (int v = 0; v < Vn; ++v) P[0][i][v] = x[v] * rz + EPSF;
        }
    }
    __syncthreads();

    // per-lane block-floating-point alpha state
    float a[KPL];
    int   E = 0;
    bool  zf = false;       // lane-all-zero flag
    float P5 = 0.f, P6 = 0.f;  // incoming neighbor mantissas (pre-renorm)
    int   Enb = SENT;          // incoming neighbor exponent (scale of P5/P6)

    if (wid == 0) {
        #pragma unroll
        for (int k = 0; k < KPL; ++k) {
            const int s = lane * KPL + k;
            a[k] = (s <= 1) ? P[0][0][poff[k]] : 0.f;
        }
        zf = (lane > 0);   // only s=0,1 (lane 0) reachable at t=0
        const int Ecomm = zf ? SENT : E;
        P6  = __shfl_up(a[6], 1, 64);
        P5  = __shfl_up(a[5], 1, 64);
        Enb = __shfl_up(Ecomm, 1, 64);
        if (lane == 0) { P6 = 0.f; P5 = 0.f; Enb = SENT; }
    }

    for (int c = 0; c < nch; ++c) {
        if (wid == 1) {
            // stage chunk c+1 while wave 0 computes chunk c
            if (c + 1 < nch) {
                const int base = (c + 1) * CHUNK;
                const int fill = min(CHUNK, tend - base);
                float (*Pb)[PSTR] = P[(c + 1) & 1];
                for (int i = lane; i < fill; i += 64) {
                    const float* row = lg + (size_t)(base + i) * Vn;
                    float x[Vn]; float m = -INFINITY;
                    #pragma unroll
                    for (int v = 0; v < Vn; ++v) { x[v] = row[v]; m = fmaxf(m, x[v]); }
                    float z = 0.f;
                    #pragma unroll
                    for (int v = 0; v < Vn; ++v) { x[v] = __expf(x[v] - m); z += x[v]; }
                    const float rz = 1.0f / z;
                    #pragma unroll
                    for (int v = 0; v < Vn; ++v) Pb[i][v] = x[v] * rz + EPSF;
                }
            }
        } else {
            const int base = c * CHUNK;
            const int t0 = (c == 0) ? 1 : base;
            const int t1 = min(base + CHUNK, tend);
            const float (*Pc)[PSTR] = P[c & 1];

            float pv[KPL];
            #pragma unroll
            for (int k = 0; k < KPL; ++k) pv[k] = Pc[t0 - base][poff[k]];

            for (int t = t0; t < t1; ++t) {
                // prefetch next step's probs (off the dependency chain)
                const int tln = (t + 1 < t1) ? (t + 1 - base) : (t - base);
                float pvn[KPL];
                #pragma unroll
                for (int k = 0; k < KPL; ++k) pvn[k] = Pc[tln][poff[k]];

                // align own + neighbor values to common scale En (downscale only)
                const int Eeff = zf ? SENT : E;
                const int En   = max(Eeff, Enb);
                const int dn   = E - En;      // <=0 whenever a != 0
                const int db   = Enb - En;    // <=0

                float A[KPL];
                #pragma unroll
                for (int k = 0; k < KPL; ++k) A[k] = ldexpf(a[k], dn);
                const float B6 = ldexpf(P6, db);
                const float B5 = ldexpf(P5, db);

                // alpha'[s] = (a[s] + a[s-1] + skip*a[s-2]) * p[ext_s], scale 2^En
                float n[KPL];
                n[0] = (A[0] + B6   + skipm[0] * B5)   * pv[0];
                n[1] = (A[1] + A[0] + skipm[1] * B6)   * pv[1];
                #pragma unroll
                for (int k = 2; k < KPL; ++k)
                    n[k] = (A[k] + A[k-1] + skipm[k] * A[k-2]) * pv[k];

                const float m = fmaxf(fmaxf(fmaxf(n[0], n[1]), fmaxf(n[2], n[3])),
                                      fmaxf(fmaxf(n[4], n[5]), n[6]));
                const bool zf2 = !(m > 0.f);

                // communicate PRE-renorm (shortens the cross-lane chain)
                const int Ecomm = zf2 ? SENT : En;
                P6  = __shfl_up(n[6], 1, 64);
                P5  = __shfl_up(n[5], 1, 64);
                Enb = __shfl_up(Ecomm, 1, 64);
                if (lane == 0) { P6 = 0.f; P5 = 0.f; Enb = SENT; }

                // per-lane renorm: max mantissa -> [0.5, 1)
                int e = 0;
                if (m > 0.f) { int ee; (void)frexpf(m, &ee); e = ee; }
                #pragma unroll
                for (int k = 0; k < KPL; ++k) a[k] = ldexpf(n[k], -e);
                E  = En + e;
                zf = zf2;

                #pragma unroll
                for (int k = 0; k < KPL; ++k) pv[k] = pvn[k];
            }
        }
        __syncthreads();
    }

    if (wid == 0) {
        #pragma unroll
        for (int k = 0; k < KPL; ++k) AF[lane * KPL + k] = a[k];
        EL[lane] = E;
    }
    __syncthreads();
    if (tid == 0) {
        const float LN2 = 0.69314718055994531f;
        const int ll = label_length[b];
        const int s1 = 2 * ll;
        const int s2 = max(2 * ll - 1, 0);
        const float v1 = AF[s1], v2 = AF[s2];
        const float l1 = (v1 > 0.f) ? (__logf(v1) + (float)EL[s1 / KPL] * LN2) : -1e30f;
        const float l2 = (v2 > 0.f) ? (__logf(v2) + (float)EL[s2 / KPL] * LN2) : -1e30f;
        const float mm = fmaxf(l1, l2);
        out[b] = -(mm + __logf(__expf(l1 - mm) + __expf(l2 - mm)));
    }
}

extern "C" void kernel_launch(void* const* d_in, const int* in_sizes, int n_in,
                              void* d_out, int out_size, void* d_ws, size_t ws_size,
                              hipStream_t stream) {
    const float* logits       = (const float*)d_in[0];
    const int*   labels       = (const int*)d_in[1];
    const int*   input_length = (const int*)d_in[2];
    const int*   label_length = (const int*)d_in[3];
    const int*   mts          = (const int*)d_in[4];
    float* out = (float*)d_out;

    ctc_bfp_kernel<<<Bn, 128, 0, stream>>>(logits, labels, input_length,
                                           label_length, mts, out);
}

// Round 4
// 273.604 us; speedup vs baseline: 1.6438x; 1.4297x over previous
//
#include <hip/hip_runtime.h>
#include <math.h>

// Problem constants: B=64, T=2000, V=29, L=200
#define Bn 64
#define Tn 2000
#define Vn 29
#define Ln 200
#define Sn 401              // 2L+1 lattice states
#define BLANKC 28
#define EPSF  1e-7f
#define CHUNK 128           // time steps of linear probs per LDS buffer
#define TSTR  132           // floats per symbol row (128 + pad, 16B-aligned quads)
#define SENT  (-(1 << 20))  // exponent sentinel for all-zero lanes

__device__ __forceinline__ float getc(const float4& v, int u) {
    return u == 0 ? v.x : u == 1 ? v.y : u == 2 ? v.z : v.w;
}

__global__ __launch_bounds__(128, 1)
void ctc_r4_kernel(const float* __restrict__ logits,
                   const int*   __restrict__ labels,
                   const int*   __restrict__ input_length,
                   const int*   __restrict__ label_length,
                   const int*   __restrict__ mts_ptr,
                   float*       __restrict__ out)
{
    // transposed probs: P[buf][v][t], t-contiguous, quad-aligned
    __shared__ __align__(16) float Pbuf[2 * Vn * TSTR];
    __shared__ float AF[512];
    __shared__ int   EL[64];

    const int b    = blockIdx.x;
    const int tid  = threadIdx.x;
    const int wid  = tid >> 6;            // wave 0: DP, wave 1: staging
    const int lane = tid & 63;
    const float* lg  = logits + (size_t)b * Tn * Vn;
    const int*   lab = labels + b * Ln;

    const int mts = *mts_ptr;
    const int ctc_len = (int)floorf((float)(input_length[b] * Tn) / (float)mts);
    const int tend = min(max(ctc_len, 1), Tn);
    const int nch  = (tend + CHUNK - 1) / CHUNK;

    // per-lane odd-state metadata for window i=2..15 (state s = 8*lane - 8 + i)
    int   symOdd[7];
    float skOdd[7];
    #pragma unroll
    for (int kk = 0; kk < 7; ++kk) {
        const int i = 2 * kk + 3;
        const int s = 8 * lane - 8 + i;   // odd
        int e = BLANKC; float sk = 0.f;
        if (s >= 0 && s < Sn) {
            const int li = (s - 1) >> 1;
            e = lab[li];
            if (s >= 3 && e != lab[li - 1]) sk = 1.f;
        }
        symOdd[kk] = e; skOdd[kk] = sk;
    }

    // staging: linear probs (softmax + eps) into transposed LDS
    auto stage = [&](int base, int fill, float* Pb, int idx, int stride) {
        for (int i = idx; i < fill; i += stride) {
            const float* row = lg + (size_t)(base + i) * Vn;
            float x[Vn]; float mm = -INFINITY;
            #pragma unroll
            for (int v = 0; v < Vn; ++v) { x[v] = row[v]; mm = fmaxf(mm, x[v]); }
            float z = 0.f;
            #pragma unroll
            for (int v = 0; v < Vn; ++v) { x[v] = __expf(x[v] - mm); z += x[v]; }
            const float rz = 1.0f / z;
            #pragma unroll
            for (int v = 0; v < Vn; ++v) Pb[v * TSTR + i] = x[v] * rz + EPSF;
        }
    };

    // prologue: stage chunk 0 with all 128 threads
    stage(0, min(CHUNK, tend), Pbuf, tid, 128);
    __syncthreads();

    // per-lane BFP alpha state
    float a[8] = {0.f, 0.f, 0.f, 0.f, 0.f, 0.f, 0.f, 0.f};
    int   E = 0;
    bool  zf = true;
    if (wid == 0) {
        if (lane == 0) {
            a[0] = Pbuf[BLANKC * TSTR];       // state 0 at t=0
            a[1] = Pbuf[symOdd[3] * TSTR];    // state 1 at t=0 (i=9 -> s=1)
        }
        zf = (lane != 0);
    }

    for (int c = 0; c < nch; ++c) {
        if (wid == 1) {
            if (c + 1 < nch) {
                const int base = (c + 1) * CHUNK;
                stage(base, min(CHUNK, tend - base),
                      Pbuf + ((c + 1) & 1) * (Vn * TSTR), lane, 64);
            }
        } else {
            float* Pc = Pbuf + (c & 1) * (Vn * TSTR);
            const int rbase = c * CHUNK;
            const int rcnt  = min(CHUNK, tend - rbase);
            const int nr    = (rcnt + 3) >> 2;

            for (int j = 0; j < nr; ++j) {
                const int t0   = rbase + 4 * j;
                const int toff = 4 * j;

                // prob quads for this round: rows t0..t0+3 per symbol
                float4 pf[7];
                #pragma unroll
                for (int kk = 0; kk < 7; ++kk)
                    pf[kk] = *(const float4*)(Pc + symOdd[kk] * TSTR + toff);
                const float4 pb = *(const float4*)(Pc + BLANKC * TSTR + toff);

                // one communication round: neighbor's 8 states + exponent
                float w[16];
                #pragma unroll
                for (int k = 0; k < 8; ++k) w[k] = __shfl_up(a[k], 1, 64);
                int Enb = __shfl_up(zf ? SENT : E, 1, 64);
                if (lane == 0) {
                    #pragma unroll
                    for (int k = 0; k < 8; ++k) w[k] = 0.f;
                    Enb = SENT;
                }

                const int Eeff = zf ? SENT : E;
                const int En   = max(Eeff, Enb);
                const int db   = Enb - En;
                const int dn   = E - En;
                #pragma unroll
                for (int k = 0; k < 8; ++k) w[k] = ldexpf(w[k], db);
                #pragma unroll
                for (int k = 0; k < 8; ++k) w[8 + k] = ldexpf(a[k], dn);

                // 4 local DP steps over the shrinking dependency window
                #pragma unroll
                for (int u = 0; u < 4; ++u) {
                    const int t = t0 + u;
                    if (t >= tend) break;
                    if (t == 0) continue;   // t=0 is the init condition
                    #pragma unroll
                    for (int ii = 0; ii < 14 - 2 * u; ++ii) {
                        const int i = 15 - ii;
                        if (i & 1) {
                            const int kk = (i - 3) >> 1;
                            w[i] = (fmaf(skOdd[kk], w[i - 2], w[i]) + w[i - 1])
                                   * getc(pf[kk], u);
                        } else {
                            w[i] = (w[i] + w[i - 1]) * getc(pb, u);
                        }
                    }
                }

                // per-lane renorm of own 8 states
                float mx = w[8];
                #pragma unroll
                for (int k = 1; k < 8; ++k) mx = fmaxf(mx, w[8 + k]);
                int e; (void)frexpf(mx, &e);   // e=0 when mx==0
                #pragma unroll
                for (int k = 0; k < 8; ++k) a[k] = ldexpf(w[8 + k], -e);
                E  = En + e;
                zf = !(mx > 0.f);
            }
        }
        __syncthreads();
    }

    if (wid == 0) {
        #pragma unroll
        for (int k = 0; k < 8; ++k) AF[lane * 8 + k] = a[k];
        EL[lane] = E;
    }
    __syncthreads();
    if (tid == 0) {
        const float LN2 = 0.69314718055994531f;
        const int ll = label_length[b];
        const int s1 = 2 * ll;
        const int s2 = max(2 * ll - 1, 0);
        const float v1 = AF[s1], v2 = AF[s2];
        const float l1 = (v1 > 0.f) ? (__logf(v1) + (float)EL[s1 >> 3] * LN2) : -1e30f;
        const float l2 = (v2 > 0.f) ? (__logf(v2) + (float)EL[s2 >> 3] * LN2) : -1e30f;
        const float mm = fmaxf(l1, l2);
        out[b] = -(mm + __logf(__expf(l1 - mm) + __expf(l2 - mm)));
    }
}

extern "C" void kernel_launch(void* const* d_in, const int* in_sizes, int n_in,
                              void* d_out, int out_size, void* d_ws, size_t ws_size,
                              hipStream_t stream) {
    const float* logits       = (const float*)d_in[0];
    const int*   labels       = (const int*)d_in[1];
    const int*   input_length = (const int*)d_in[2];
    const int*   label_length = (const int*)d_in[3];
    const int*   mts          = (const int*)d_in[4];
    float* out = (float*)d_out;

    ctc_r4_kernel<<<Bn, 128, 0, stream>>>(logits, labels, input_length,
                                          label_length, mts, out);
}

// Round 5
// 267.435 us; speedup vs baseline: 1.6818x; 1.0231x over previous
//
#include <hip/hip_runtime.h>
#include <math.h>

// Problem constants: B=64, T=2000, V=29, L=200
#define Bn 64
#define Tn 2000
#define Vn 29
#define Ln 200
#define Sn 401              // 2L+1 lattice states
#define BLANKC 28
#define EPSF  1e-7f
#define CHUNK 128           // time steps of linear probs per LDS buffer
#define TSTR  132           // floats per symbol row (128 + pad, 16B-aligned quads)
#define SENT  (-(1 << 20))  // exponent sentinel for all-zero lanes

__device__ __forceinline__ float getc(const float4& v, int u) {
    return u == 0 ? v.x : u == 1 ? v.y : u == 2 ? v.z : v.w;
}

// One DP round: consume quads PIN (4 time steps at T0..T0+3), align own+neighbor
// BFP state, run 4 local DP steps, prefetch POUT quads for the next round,
// communicate pre-renorm states to lane+1, then renorm locally (overlapping the
// in-flight shuffles/loads).
#define ROUNDM(T0, PIN, POUT, PC, TOFFN) do {                                   \
  const int Eeff_ = zf ? SENT : E;                                              \
  const int En_ = max(Eeff_, Enb);                                              \
  const int db_ = Enb - En_, dn_ = E - En_;                                     \
  float w[16];                                                                  \
  _Pragma("unroll") for (int k = 0; k < 8; ++k) w[k] = ldexpf(nb[k], db_);      \
  _Pragma("unroll") for (int k = 0; k < 8; ++k) w[8 + k] = ldexpf(a[k], dn_);   \
  _Pragma("unroll") for (int u = 0; u < 4; ++u) {                               \
    const int t_ = (T0) + u;                                                    \
    if (t_ != 0 && t_ < tend) {                                                 \
      _Pragma("unroll") for (int ii = 0; ii < 14 - 2 * u; ++ii) {               \
        const int i = 15 - ii;                                                  \
        if (i & 1) {                                                            \
          const int kk = (i - 3) >> 1;                                          \
          w[i] = (fmaf(skOdd[kk], w[i - 2], w[i]) + w[i - 1]) * getc(PIN[kk], u);\
        } else {                                                                \
          w[i] = (w[i] + w[i - 1]) * getc(PIN[7], u);                           \
        }                                                                       \
      }                                                                         \
    }                                                                           \
  }                                                                             \
  { const int tf_ = (TOFFN) > 124 ? 124 : (TOFFN);                              \
    _Pragma("unroll") for (int kk = 0; kk < 7; ++kk)                            \
      POUT[kk] = *(const float4*)((PC) + symOdd[kk] * TSTR + tf_);              \
    POUT[7] = *(const float4*)((PC) + BLANKC * TSTR + tf_); }                   \
  _Pragma("unroll") for (int k = 0; k < 8; ++k) nb[k] = __shfl_up(w[8 + k], 1, 64);\
  float mx_ = fmaxf(fmaxf(fmaxf(w[8], w[9]), fmaxf(w[10], w[11])),              \
                    fmaxf(fmaxf(w[12], w[13]), fmaxf(w[14], w[15])));           \
  const bool zf2_ = !(mx_ > 0.f);                                               \
  Enb = __shfl_up(zf2_ ? SENT : En_, 1, 64);                                    \
  if (lane == 0) {                                                              \
    _Pragma("unroll") for (int k = 0; k < 8; ++k) nb[k] = 0.f;                  \
    Enb = SENT;                                                                 \
  }                                                                             \
  int e_; (void)frexpf(mx_, &e_);                                               \
  _Pragma("unroll") for (int k = 0; k < 8; ++k) a[k] = ldexpf(w[8 + k], -e_);   \
  E = En_ + e_; zf = zf2_;                                                      \
} while (0)

__global__ __launch_bounds__(128, 1)
void ctc_pipe_kernel(const float* __restrict__ logits,
                     const int*   __restrict__ labels,
                     const int*   __restrict__ input_length,
                     const int*   __restrict__ label_length,
                     const int*   __restrict__ mts_ptr,
                     float*       __restrict__ out)
{
    // transposed probs: P[buf][v][t], t-contiguous, quad-aligned
    __shared__ __align__(16) float Pbuf[2 * Vn * TSTR];
    __shared__ float AF[512];
    __shared__ int   EL[64];

    const int b    = blockIdx.x;
    const int tid  = threadIdx.x;
    const int wid  = tid >> 6;            // wave 0: DP, wave 1: staging
    const int lane = tid & 63;
    const float* lg  = logits + (size_t)b * Tn * Vn;
    const int*   lab = labels + b * Ln;

    const int mts = *mts_ptr;
    const int ctc_len = (int)floorf((float)(input_length[b] * Tn) / (float)mts);
    const int tend = min(max(ctc_len, 1), Tn);
    const int nch  = (tend + CHUNK - 1) / CHUNK;

    // per-lane odd-state metadata for window i=2..15 (state s = 8*lane - 8 + i)
    int   symOdd[7];
    float skOdd[7];
    #pragma unroll
    for (int kk = 0; kk < 7; ++kk) {
        const int i = 2 * kk + 3;
        const int s = 8 * lane - 8 + i;   // odd
        int e = BLANKC; float sk = 0.f;
        if (s >= 0 && s < Sn) {
            const int li = (s - 1) >> 1;
            e = lab[li];
            if (s >= 3 && e != lab[li - 1]) sk = 1.f;
        }
        symOdd[kk] = e; skOdd[kk] = sk;
    }

    // staging: linear probs (softmax + eps) into transposed LDS
    auto stage = [&](int base, int fill, float* Pb, int idx, int stride) {
        for (int i = idx; i < fill; i += stride) {
            const float* row = lg + (size_t)(base + i) * Vn;
            float x[Vn]; float mm = -INFINITY;
            #pragma unroll
            for (int v = 0; v < Vn; ++v) { x[v] = row[v]; mm = fmaxf(mm, x[v]); }
            float z = 0.f;
            #pragma unroll
            for (int v = 0; v < Vn; ++v) { x[v] = __expf(x[v] - mm); z += x[v]; }
            const float rz = 1.0f / z;
            #pragma unroll
            for (int v = 0; v < Vn; ++v) Pb[v * TSTR + i] = x[v] * rz + EPSF;
        }
    };

    // prologue: stage chunk 0 with all 128 threads
    stage(0, min(CHUNK, tend), Pbuf, tid, 128);
    __syncthreads();

    // per-lane BFP alpha state
    float a[8] = {0.f, 0.f, 0.f, 0.f, 0.f, 0.f, 0.f, 0.f};
    float nb[8];
    int   E = 0, Enb = SENT;
    bool  zf = true;
    float4 qA[8], qB[8];

    if (wid == 0) {
        __builtin_amdgcn_s_setprio(1);
        if (lane == 0) {
            a[0] = Pbuf[BLANKC * TSTR];       // state 0 at t=0
            a[1] = Pbuf[symOdd[3] * TSTR];    // state 1 at t=0 (i=9 -> s=1)
        }
        zf = (lane != 0);
        #pragma unroll
        for (int k = 0; k < 8; ++k) nb[k] = __shfl_up(a[k], 1, 64);
        Enb = __shfl_up(zf ? SENT : 0, 1, 64);
        if (lane == 0) {
            #pragma unroll
            for (int k = 0; k < 8; ++k) nb[k] = 0.f;
            Enb = SENT;
        }
    }

    for (int c = 0; c < nch; ++c) {
        if (wid == 1) {
            if (c + 1 < nch) {
                const int base = (c + 1) * CHUNK;
                stage(base, min(CHUNK, tend - base),
                      Pbuf + ((c + 1) & 1) * (Vn * TSTR), lane, 64);
            }
        } else {
            float* Pc = Pbuf + (c & 1) * (Vn * TSTR);
            const int rbase = c * CHUNK;
            const int rcnt  = min(CHUNK, tend - rbase);
            const int nr    = (rcnt + 3) >> 2;

            // cold load for round 0 of this chunk
            #pragma unroll
            for (int kk = 0; kk < 7; ++kk)
                qA[kk] = *(const float4*)(Pc + symOdd[kk] * TSTR);
            qA[7] = *(const float4*)(Pc + BLANKC * TSTR);

            // rounds in pairs with A/B register rotation (dummy tail round is
            // fully guarded: updates skipped, align/renorm idempotent)
            for (int jj = 0; jj < nr; jj += 2) {
                ROUNDM(rbase + 4 * jj,       qA, qB, Pc, 4 * (jj + 1));
                ROUNDM(rbase + 4 * (jj + 1), qB, qA, Pc, 4 * (jj + 2));
            }
        }
        __syncthreads();
    }

    if (wid == 0) {
        __builtin_amdgcn_s_setprio(0);
        #pragma unroll
        for (int k = 0; k < 8; ++k) AF[lane * 8 + k] = a[k];
        EL[lane] = E;
    }
    __syncthreads();
    if (tid == 0) {
        const float LN2 = 0.69314718055994531f;
        const int ll = label_length[b];
        const int s1 = 2 * ll;
        const int s2 = max(2 * ll - 1, 0);
        const float v1 = AF[s1], v2 = AF[s2];
        const float l1 = (v1 > 0.f) ? (__logf(v1) + (float)EL[s1 >> 3] * LN2) : -1e30f;
        const float l2 = (v2 > 0.f) ? (__logf(v2) + (float)EL[s2 >> 3] * LN2) : -1e30f;
        const float mm = fmaxf(l1, l2);
        out[b] = -(mm + __logf(__expf(l1 - mm) + __expf(l2 - mm)));
    }
}

extern "C" void kernel_launch(void* const* d_in, const int* in_sizes, int n_in,
                              void* d_out, int out_size, void* d_ws, size_t ws_size,
                              hipStream_t stream) {
    const float* logits       = (const float*)d_in[0];
    const int*   labels       = (const int*)d_in[1];
    const int*   input_length = (const int*)d_in[2];
    const int*   label_length = (const int*)d_in[3];
    const int*   mts          = (const int*)d_in[4];
    float* out = (float*)d_out;

    ctc_pipe_kernel<<<Bn, 128, 0, stream>>>(logits, labels, input_length,
                                            label_length, mts, out);
}

// Round 6
// 161.886 us; speedup vs baseline: 2.7782x; 1.6520x over previous
//
#include <hip/hip_runtime.h>
#include <math.h>

// Problem constants: B=64, T=2000, V=29, L=200
#define Bn 64
#define Tn 2000
#define Vn 29
#define Ln 200
#define Sn 401              // 2L+1 lattice states
#define BLANKC 28
#define EPSF  1e-7f
#define CHUNK 128           // time steps of linear probs per LDS buffer
#define TSTR  132           // floats per symbol row (128 + pad, 16B-aligned quads)
#define SENT  (-(1 << 20))  // exponent sentinel for all-zero lanes
#define LN2F  0.69314718055994531f

__device__ __forceinline__ float getc(const float4& v, int u) {
    return u == 0 ? v.x : u == 1 ? v.y : u == 2 ? v.z : v.w;
}
__device__ __forceinline__ float bpermf(int addr, float x) {
    return __int_as_float(__builtin_amdgcn_ds_bpermute(addr, __float_as_int(x)));
}

// ---------- forward round: 4 time steps; lane owns states 8l..8l+7 at w[8..15],
// neighbor (lane-1) trailing states at w[0..7]. alpha'[s]=(a[s]+a[s-1]+sk*a[s-2])*p[ext[s]]
#define ROUNDF(T0, PIN, POUT, PC, TOFFN) do {                                    \
  const int Eeff_ = zf ? SENT : E;                                               \
  const int En_   = max(Eeff_, Enb);                                             \
  const int db_ = Enb - En_, dn_ = E - En_;                                      \
  float w[16];                                                                   \
  _Pragma("unroll") for (int k = 0; k < 8; ++k) w[k]     = ldexpf(nb[k], db_);   \
  _Pragma("unroll") for (int k = 0; k < 8; ++k) w[8 + k] = ldexpf(a[k],  dn_);   \
  _Pragma("unroll") for (int u = 0; u < 4; ++u) {                                \
    const int t_ = (T0) + u;                                                     \
    if (t_ != 0 && t_ < TFe) {                                                   \
      _Pragma("unroll") for (int ii = 0; ii < 14 - 2 * u; ++ii) {                \
        const int i = 15 - ii;                                                   \
        if (i & 1) {                                                             \
          const int kk = (i - 3) >> 1;                                           \
          w[i] = (fmaf(skOdd[kk], w[i-2], w[i]) + w[i-1]) * getc(PIN[kk], u);    \
        } else {                                                                 \
          w[i] = (w[i] + w[i-1]) * getc(PIN[7], u);                              \
        } } } }                                                                  \
  { const int tf_ = (TOFFN) > (CHUNK-4) ? (CHUNK-4) : (TOFFN);                   \
    _Pragma("unroll") for (int kk = 0; kk < 7; ++kk)                             \
      POUT[kk] = *(const float4*)((PC) + soffF[kk] + tf_);                       \
    POUT[7] = *(const float4*)((PC) + BLANKC * TSTR + tf_); }                    \
  _Pragma("unroll") for (int k = 0; k < 8; ++k) nb[k] = bpermf(pup, w[8 + k]);   \
  float mx_ = fmaxf(fmaxf(fmaxf(w[8],w[9]),fmaxf(w[10],w[11])),                  \
                    fmaxf(fmaxf(w[12],w[13]),fmaxf(w[14],w[15])));               \
  const bool z2_ = !(mx_ > 0.f);                                                 \
  Enb = __builtin_amdgcn_ds_bpermute(pup, z2_ ? SENT : En_);                     \
  if (lane == 0) {                                                               \
    _Pragma("unroll") for (int k = 0; k < 8; ++k) nb[k] = 0.f;                   \
    Enb = SENT; }                                                                \
  int e_; (void)frexpf(mx_, &e_);                                                \
  _Pragma("unroll") for (int k = 0; k < 8; ++k) a[k] = ldexpf(w[8 + k], -e_);    \
  E = En_ + e_; zf = z2_;                                                        \
} while (0)

// ---------- backward round: lane owns states at w[0..7], neighbor (lane+1) at
// w[8..15]. beta_{t-1}[s] = q[s] + q[s+1] + sk[s+2]*q[s+2], q[s']=beta_t[s']*p_t[ext[s']]
#define ROUNDB(S0, PIN, POUT, PC, TOFFN) do {                                    \
  const int Eeff_ = zf ? SENT : E;                                               \
  const int En_   = max(Eeff_, Enb);                                             \
  const int db_ = Enb - En_, dn_ = E - En_;                                      \
  float w[16];                                                                   \
  _Pragma("unroll") for (int k = 0; k < 8; ++k) w[k]     = ldexpf(a[k],  dn_);   \
  _Pragma("unroll") for (int k = 0; k < 8; ++k) w[8 + k] = ldexpf(nb[k], db_);   \
  _Pragma("unroll") for (int u = 0; u < 4; ++u) {                                \
    const int s_ = (S0) + u;                                                     \
    if (s_ < TBe) {                                                              \
      float q[16];                                                               \
      _Pragma("unroll") for (int j = 0; j < 16; ++j) {                           \
        if (j < 16 - 2 * u)                                                      \
          q[j] = w[j] * ((j & 1) ? getc(PIN[(j-1)>>1], u) : getc(PIN[8], u));    \
        else q[j] = 0.f; }                                                       \
      _Pragma("unroll") for (int i = 0; i < 14; ++i) {                           \
        if (i < 14 - 2 * u) {                                                    \
          if (i & 1) w[i] = fmaf(skB[(i-1)>>1], q[i+2], q[i]) + q[i+1];          \
          else       w[i] = q[i] + q[i+1];                                       \
        } } } }                                                                  \
  { const int tf_ = (TOFFN) > (CHUNK-4) ? (CHUNK-4) : (TOFFN);                   \
    _Pragma("unroll") for (int m = 0; m < 8; ++m)                                \
      POUT[m] = *(const float4*)((PC) + soffB[m] + tf_);                         \
    POUT[8] = *(const float4*)((PC) + BLANKC * TSTR + tf_); }                    \
  _Pragma("unroll") for (int k = 0; k < 8; ++k) nb[k] = bpermf(pdn, w[k]);       \
  float mx_ = fmaxf(fmaxf(fmaxf(w[0],w[1]),fmaxf(w[2],w[3])),                    \
                    fmaxf(fmaxf(w[4],w[5]),fmaxf(w[6],w[7])));                   \
  const bool z2_ = !(mx_ > 0.f);                                                 \
  Enb = __builtin_amdgcn_ds_bpermute(pdn, z2_ ? SENT : En_);                     \
  if (lane == 63) {                                                              \
    _Pragma("unroll") for (int k = 0; k < 8; ++k) nb[k] = 0.f;                   \
    Enb = SENT; }                                                                \
  int e_; (void)frexpf(mx_, &e_);                                                \
  _Pragma("unroll") for (int k = 0; k < 8; ++k) a[k] = ldexpf(w[k], -e_);        \
  E = En_ + e_; zf = z2_;                                                        \
} while (0)

__global__ __launch_bounds__(256, 1)
void ctc_fb_kernel(const float* __restrict__ logits,
                   const int*   __restrict__ labels,
                   const int*   __restrict__ input_length,
                   const int*   __restrict__ label_length,
                   const int*   __restrict__ mts_ptr,
                   float*       __restrict__ out)
{
    __shared__ __align__(16) float PFb[2][Vn * TSTR];   // fwd prob dbuf
    __shared__ __align__(16) float PBb[2][Vn * TSTR];   // bwd prob dbuf (time-reversed slots)

    const int b    = blockIdx.x;
    const int tid  = threadIdx.x;
    const int wid  = tid >> 6;    // 0: fwd DP, 1: bwd DP, 2: fwd stage, 3: bwd stage
    const int lane = tid & 63;
    const float* lg  = logits + (size_t)b * Tn * Vn;
    const int*   lab = labels + b * Ln;

    const int mts = *mts_ptr;
    const int ctc_len = (int)floorf((float)(input_length[b] * Tn) / (float)mts);
    const int tend = min(max(ctc_len, 1), Tn);
    const int tm   = (tend - 1) >> 1;      // meeting point
    const int TFe  = tm + 1;               // fwd consumes probs t in [0, TFe)
    const int TBe  = tend - 1 - tm;        // bwd consumes slots i=tend-1-t in [0, TBe)
    const int nchF = (TFe + CHUNK - 1) / CHUNK;
    const int nchB = (TBe + CHUNK - 1) / CHUNK;
    const int nch2 = max(nchF, nchB);

    const int pup = ((lane - 1) & 63) << 2;   // bpermute byte addr: lane-1
    const int pdn = ((lane + 1) & 63) << 2;   // lane+1

    // ---- fwd metadata: window pos i=2kk+3, state s = 8*lane-8+i ----
    int soffF[7]; float skOdd[7];
    #pragma unroll
    for (int kk = 0; kk < 7; ++kk) {
        const int s = 8 * lane - 5 + 2 * kk;
        int e = BLANKC; float sk = 0.f;
        if (s >= 0 && s < Sn) {
            const int li = (s - 1) >> 1;
            e = lab[li];
            if (s >= 3 && e != lab[li - 1]) sk = 1.f;
        }
        soffF[kk] = e * TSTR; skOdd[kk] = sk;
    }
    // ---- bwd metadata: pos j=2m+1, state s = 8*lane+j ----
    int soffB[8]; float skB[7];
    #pragma unroll
    for (int m = 0; m < 8; ++m) {
        const int s = 8 * lane + 2 * m + 1;
        soffB[m] = ((s < Sn) ? lab[(s - 1) >> 1] : BLANKC) * TSTR;
    }
    #pragma unroll
    for (int m = 0; m < 7; ++m) {
        const int s = 8 * lane + 2 * m + 3;
        float sk = 0.f;
        if (s >= 3 && s < Sn) {
            const int li = (s - 1) >> 1;
            if (lab[li] != lab[li - 1]) sk = 1.f;
        }
        skB[m] = sk;
    }

    // staging helpers: linear probs (softmax + eps), transposed [v][slot]
    auto srow = [&](const float* row, float* Pb, int i) {
        float x[Vn]; float mm = -INFINITY;
        #pragma unroll
        for (int v = 0; v < Vn; ++v) { x[v] = row[v]; mm = fmaxf(mm, x[v]); }
        float z = 0.f;
        #pragma unroll
        for (int v = 0; v < Vn; ++v) { x[v] = __expf(x[v] - mm); z += x[v]; }
        const float rz = 1.0f / z;
        #pragma unroll
        for (int v = 0; v < Vn; ++v) Pb[v * TSTR + i] = x[v] * rz + EPSF;
    };
    auto stageF = [&](int c) {
        const int base = c * CHUNK;
        const int fill = min(CHUNK, TFe - base);
        float* Pb = PFb[c & 1];
        for (int i = lane; i < fill; i += 64)
            srow(lg + (size_t)(base + i) * Vn, Pb, i);
    };
    auto stageB = [&](int c) {
        const int base = c * CHUNK;
        const int fill = min(CHUNK, TBe - base);
        float* Pb = PBb[c & 1];
        for (int i = lane; i < fill; i += 64)
            srow(lg + (size_t)(tend - 1 - (base + i)) * Vn, Pb, i);
    };

    if (wid == 2) stageF(0);
    if (wid == 3 && TBe > 0) stageB(0);
    __syncthreads();

    // per-lane BFP state (each DP wave uses its own registers)
    float a[8] = {0.f,0.f,0.f,0.f,0.f,0.f,0.f,0.f};
    float nb[8];
    int   E = 0, Enb = SENT;
    bool  zf = true;
    float4 qA[9], qB[9];

    if (wid == 0) {
        __builtin_amdgcn_s_setprio(1);
        if (lane == 0) {
            a[0] = PFb[0][BLANKC * TSTR];   // alpha0[0]
            a[1] = PFb[0][soffF[3]];        // alpha0[1] (lane0: kk=3 -> s=1 -> lab[0])
        }
        zf = (lane != 0);
        #pragma unroll
        for (int k = 0; k < 8; ++k) nb[k] = bpermf(pup, a[k]);
        Enb = __builtin_amdgcn_ds_bpermute(pup, zf ? SENT : 0);
        if (lane == 0) {
            #pragma unroll
            for (int k = 0; k < 8; ++k) nb[k] = 0.f;
            Enb = SENT;
        }
    } else if (wid == 1) {
        __builtin_amdgcn_s_setprio(1);
        const int ll = label_length[b];
        const int s1 = 2 * ll, s2 = max(2 * ll - 1, 0);
        #pragma unroll
        for (int k = 0; k < 8; ++k) {
            const int s = 8 * lane + k;
            a[k] = (s == s1 || s == s2) ? 0.5f : 0.f;   // beta_{tend-1}=1 (0.5*2^1)
        }
        E  = 1;
        zf = !(((s1 >> 3) == lane) || ((s2 >> 3) == lane));
        #pragma unroll
        for (int k = 0; k < 8; ++k) nb[k] = bpermf(pdn, a[k]);
        Enb = __builtin_amdgcn_ds_bpermute(pdn, zf ? SENT : E);
        if (lane == 63) {
            #pragma unroll
            for (int k = 0; k < 8; ++k) nb[k] = 0.f;
            Enb = SENT;
        }
    }

    for (int c = 0; c < nch2; ++c) {
        if (wid == 2) {
            if (c + 1 < nchF) stageF(c + 1);
        } else if (wid == 3) {
            if (c + 1 < nchB) stageB(c + 1);
        } else if (wid == 0) {
            if (c < nchF) {
                float* Pc = PFb[c & 1];
                const int rbase = c * CHUNK;
                const int rcnt  = min(CHUNK, TFe - rbase);
                const int nr    = (rcnt + 3) >> 2;
                #pragma unroll
                for (int kk = 0; kk < 7; ++kk)
                    qA[kk] = *(const float4*)(Pc + soffF[kk]);
                qA[7] = *(const float4*)(Pc + BLANKC * TSTR);
                for (int jj = 0; jj < nr; jj += 2) {
                    ROUNDF(rbase + 4 * jj,       qA, qB, Pc, 4 * (jj + 1));
                    ROUNDF(rbase + 4 * (jj + 1), qB, qA, Pc, 4 * (jj + 2));
                }
            }
        } else {
            if (c < nchB) {
                float* Pc = PBb[c & 1];
                const int sbase = c * CHUNK;
                const int rcnt  = min(CHUNK, TBe - sbase);
                const int nr    = (rcnt + 3) >> 2;
                #pragma unroll
                for (int m = 0; m < 8; ++m)
                    qA[m] = *(const float4*)(Pc + soffB[m]);
                qA[8] = *(const float4*)(Pc + BLANKC * TSTR);
                for (int jj = 0; jj < nr; jj += 2) {
                    ROUNDB(sbase + 4 * jj,       qA, qB, Pc, 4 * (jj + 1));
                    ROUNDB(sbase + 4 * (jj + 1), qB, qA, Pc, 4 * (jj + 2));
                }
            }
        }
        __syncthreads();
    }

    // readout: sum_s alpha_tm[s] * beta_tm[s]  (AF/EL alias the prob buffers)
    float* AFa = PFb[0];
    int*   ELa = (int*)(PFb[0] + 512);
    float* AFb = PBb[0];
    int*   ELb = (int*)(PBb[0] + 512);

    if (wid == 0) {
        #pragma unroll
        for (int k = 0; k < 8; ++k) AFa[lane * 8 + k] = a[k];
        ELa[lane] = zf ? SENT : E;
    } else if (wid == 1) {
        #pragma unroll
        for (int k = 0; k < 8; ++k) AFb[lane * 8 + k] = a[k];
        ELb[lane] = zf ? SENT : E;
    }
    __syncthreads();

    if (wid == 0) {
        float v = 0.f;
        #pragma unroll
        for (int k = 0; k < 8; ++k)
            v = fmaf(AFa[lane * 8 + k], AFb[lane * 8 + k], v);
        const int el  = ELa[lane] + ELb[lane];
        const bool val = (v > 0.f);
        int em = val ? el : (SENT * 2);
        #pragma unroll
        for (int off = 1; off < 64; off <<= 1)
            em = max(em, __shfl_xor(em, off, 64));
        float sv = val ? ldexpf(v, el - em) : 0.f;
        #pragma unroll
        for (int off = 1; off < 64; off <<= 1)
            sv += __shfl_xor(sv, off, 64);
        if (lane == 0) out[b] = -(__logf(sv) + (float)em * LN2F);
    }
}

extern "C" void kernel_launch(void* const* d_in, const int* in_sizes, int n_in,
                              void* d_out, int out_size, void* d_ws, size_t ws_size,
                              hipStream_t stream) {
    const float* logits       = (const float*)d_in[0];
    const int*   labels       = (const int*)d_in[1];
    const int*   input_length = (const int*)d_in[2];
    const int*   label_length = (const int*)d_in[3];
    const int*   mts          = (const int*)d_in[4];
    float* out = (float*)d_out;

    ctc_fb_kernel<<<Bn, 256, 0, stream>>>(logits, labels, input_length,
                                          label_length, mts, out);
}